// Round 11
// baseline (146.527 us; speedup 1.0000x reference)
//
#include <hip/hip_runtime.h>

// Problem constants (from reference)
#define B_ 32
#define C_ 32
#define T_ 8192
#define N_ 256
#define P_ 6
#define TV_ (T_ - P_ + 1)   // valid conv length = 8187
#define TILE_T 128          // t-slice per block
#define REP 10              // measurement replicas (z=0 stores; z>0 compute-only)

// =============================================================================
// MEASUREMENT ROUND: r10 structure, k_fuse replicated x10 in gridDim.z so it
// exceeds the 150-166us harness poison fills and surfaces in the PMC top-5
// WITH counters (VALUBusy / Occupancy / FETCH / WRITE / LDS-conflict / dur).
// z=0 replica stores (correct output); z>0 replicas run the identical
// decode+LDS+match pipeline, store suppressed, orv kept live via asm.
// =============================================================================

// ---------------------------------------------------------------------------
// Kernel 0 (verbatim r5): discretize patterns -> byte-SIMD match tables.
// tabs[n][12]: dwords 0..5 = xs[p] (XOR splat), 6..11 = om[p] (active mask).
// ---------------------------------------------------------------------------
__global__ void k_disc(const float* __restrict__ pat, unsigned* __restrict__ tabs) {
    int tid = blockIdx.x * blockDim.x + threadIdx.x;
    if (tid >= P_ * N_) return;
    int p = tid / N_;
    int n = tid - p * N_;
    float maxv = -3.402823466e+38f;
    float sum = 0.0f;
    unsigned mask = 0u;
    #pragma unroll
    for (int c = 0; c < C_; ++c) {
        float v = pat[((size_t)c * P_ + p) * N_ + n];
        sum += v;
        if (v > maxv) { maxv = v; mask = (1u << c); }
        else if (v == maxv) { mask |= (1u << c); }
    }
    if (!(sum > 0.0f)) mask = 0u;
    int pc = __popc(mask);
    unsigned req = (unsigned)(__ffs((int)mask) - 1);
    unsigned xs = (pc == 1) ? req * 0x01010101u : 0x7F7F7F7Fu;
    unsigned om = (pc == 0) ? 0u : 0x80808080u;
    tabs[n * 12 + p]     = xs;
    tabs[n * 12 + 6 + p] = om;
}

// ---------------------------------------------------------------------------
// k_fuse (r10 body + replica dim): grid (64, 32, REP).
// ---------------------------------------------------------------------------
__global__ void k_fuse(const float* __restrict__ inp,
                       const unsigned* __restrict__ tabs,
                       float* __restrict__ out) {
    __shared__ unsigned s_tabs[N_ * 12];  // 12 KB
    __shared__ float4 s_part[8][32];      // 4 KB  (cg x quad partial sums)
    __shared__ float4 s_part2[8][2];      // halo partials
    __shared__ unsigned s32[34];          // 128 chars + 8 halo bytes (packed)

    int tile = blockIdx.x;                // 0..63
    int b    = blockIdx.y;                // 0..31
    int z    = blockIdx.z;                // replica; only z==0 stores
    int tid  = threadIdx.x;
    int t0   = tile * TILE_T;
    int quad = tid & 31;                  // t-quad within tile
    int cg   = tid >> 5;                  // c-group 0..7 (4 chars each)

    // ---- stage tabs -> LDS ----
    {
        const uint4* g = (const uint4*)tabs;
        uint4*       l = (uint4*)s_tabs;
        #pragma unroll
        for (int k = 0; k < 3; ++k) l[tid + 256 * k] = g[tid + 256 * k];
    }

    // ---- decode: thread (quad, cg) sums 4 c-rows at its 4 t's ----
    {
        int t = t0 + (quad << 2);
        const float* base = inp + (size_t)b * C_ * T_ + t;
        float ax = 0.f, ay = 0.f, az = 0.f, aw = 0.f;
        #pragma unroll
        for (int i = 0; i < 4; ++i) {
            int c = (cg << 2) + i;
            float4 v = *(const float4*)(base + (size_t)c * T_);
            float fc = (float)c;
            ax += fc * v.x; ay += fc * v.y; az += fc * v.z; aw += fc * v.w;
        }
        s_part[cg][quad] = make_float4(ax, ay, az, aw);
        if (quad < 2) {                   // halo quads (t0+128..t0+135)
            int th = t0 + TILE_T + (quad << 2);
            float hx = 0.f, hy = 0.f, hz = 0.f, hw = 0.f;
            if (th + 3 < T_) {
                const float* hb = inp + (size_t)b * C_ * T_ + th;
                #pragma unroll
                for (int i = 0; i < 4; ++i) {
                    int c = (cg << 2) + i;
                    float4 v = *(const float4*)(hb + (size_t)c * T_);
                    float fc = (float)c;
                    hx += fc * v.x; hy += fc * v.y; hz += fc * v.z; hw += fc * v.w;
                }
            }
            s_part2[cg][quad] = make_float4(hx, hy, hz, hw);
        }
    }
    __syncthreads();

    // ---- reduce 8 c-group partials -> packed chars words ----
    if (tid < 32) {
        float sx = 0.f, sy = 0.f, sz = 0.f, sw = 0.f;
        #pragma unroll
        for (int k = 0; k < 8; ++k) {
            float4 p = s_part[k][tid];
            sx += p.x; sy += p.y; sz += p.z; sw += p.w;
        }
        s32[tid] = ((unsigned)(sx + 0.5f))
                 | ((unsigned)(sy + 0.5f) << 8)
                 | ((unsigned)(sz + 0.5f) << 16)
                 | ((unsigned)(sw + 0.5f) << 24);
    } else if (tid < 34) {
        int hq = tid - 32;
        float sx = 0.f, sy = 0.f, sz = 0.f, sw = 0.f;
        #pragma unroll
        for (int k = 0; k < 8; ++k) {
            float4 p = s_part2[k][hq];
            sx += p.x; sy += p.y; sz += p.z; sw += p.w;
        }
        s32[32 + hq] = ((unsigned)(sx + 0.5f))
                     | ((unsigned)(sy + 0.5f) << 8)
                     | ((unsigned)(sz + 0.5f) << 16)
                     | ((unsigned)(sw + 0.5f) << 24);
    }
    __syncthreads();

    // ---- match: thread = (quad, ng=cg); loop over this ng's 32 n ----
    unsigned w0 = s32[quad], w1 = s32[quad + 1], w2 = s32[quad + 2];
    unsigned cw0 = w0;
    unsigned cw1 = __builtin_amdgcn_alignbyte(w1, w0, 1);
    unsigned cw2 = __builtin_amdgcn_alignbyte(w1, w0, 2);
    unsigned cw3 = __builtin_amdgcn_alignbyte(w1, w0, 3);
    unsigned cw4 = w1;
    unsigned cw5 = __builtin_amdgcn_alignbyte(w2, w1, 1);

    int tb = t0 + (quad << 2);
    int n0 = cg << 5;
    const uint4* tl = (const uint4*)s_tabs + (size_t)n0 * 3;
    float* obase = out + ((size_t)(b * N_ + n0)) * T_ + tb;
    bool tail = (tile == (T_ / TILE_T - 1)) && (tb + 3 >= TV_);
    bool do_store = (z == 0);

    #pragma unroll 4
    for (int g = 0; g < 32; ++g) {
        uint4 A  = tl[g * 3 + 0];
        uint4 Bv = tl[g * 3 + 1];
        uint4 Cv = tl[g * 3 + 2];

        unsigned orv;
        orv  = ((cw0 ^ A.x)  + 0x7F7F7F7FU) & Bv.z;
        orv |= ((cw1 ^ A.y)  + 0x7F7F7F7FU) & Bv.w;
        orv |= ((cw2 ^ A.z)  + 0x7F7F7F7FU) & Cv.x;
        orv |= ((cw3 ^ A.w)  + 0x7F7F7F7FU) & Cv.y;
        orv |= ((cw4 ^ Bv.x) + 0x7F7F7F7FU) & Cv.z;
        orv |= ((cw5 ^ Bv.y) + 0x7F7F7F7FU) & Cv.w;

        // keep the match chain live for z>0 replicas (anti-DCE, rule #17)
        asm volatile("" : : "v"(orv));

        if (do_store) {
            float res[4];
            #pragma unroll
            for (int j = 0; j < 4; ++j)
                res[j] = (orv & (0x80u << (8 * j))) ? 0.0f : 1.0f;

            if (tail) {
                unsigned act = Bv.z | Bv.w | Cv.x | Cv.y | Cv.z | Cv.w;
                float padf = (act == 0u) ? 1.0f : 0.0f;
                #pragma unroll
                for (int j = 0; j < 4; ++j)
                    if (tb + j >= TV_) res[j] = padf;
            }

            float4 r; r.x = res[0]; r.y = res[1]; r.z = res[2]; r.w = res[3];
            *(float4*)(obase + (size_t)g * T_) = r;
        }
    }
}

// ---------------------------------------------------------------------------
extern "C" void kernel_launch(void* const* d_in, const int* in_sizes, int n_in,
                              void* d_out, int out_size, void* d_ws, size_t ws_size,
                              hipStream_t stream) {
    const float* input_   = (const float*)d_in[0];   // (B,C,T,1) one-hot fp32
    const float* patterns = (const float*)d_in[1];   // (C,P,1,N) fp32
    float* out = (float*)d_out;                      // (B,N,T,1) fp32

    unsigned* tabs = (unsigned*)d_ws;                // [0, 12288)

    hipLaunchKernelGGL(k_disc, dim3((P_ * N_ + 255) / 256), dim3(256), 0, stream,
                       patterns, tabs);
    hipLaunchKernelGGL(k_fuse, dim3(T_ / TILE_T, B_, REP), dim3(256), 0, stream,
                       input_, tabs, out);
}

// Round 12
// 132.637 us; speedup vs baseline: 1.1047x; 1.1047x over previous
//
#include <hip/hip_runtime.h>

// Problem constants (from reference)
#define B_ 32
#define C_ 32
#define T_ 8192
#define N_ 256
#define P_ 6
#define TV_ (T_ - P_ + 1)   // valid conv length = 8187

// ---------------------------------------------------------------------------
// k_prep: ONE node replacing k_disc + k_chars (removes one graph edge).
//   blocks 0..255 : verbatim r5 k_chars body (one-hot -> chars u8 packed u32)
//   block  256    : verbatim r5 k_disc body (patterns -> tabs[n][12])
// Bodies are UNCHANGED from the proven r5 kernels; only the role split is new.
// Paired with the r5 k_final VERBATIM (33.2us = write roofline) to isolate
// the prep-fusion variable that r2 confounded with a bad k_final.
// ---------------------------------------------------------------------------
__global__ void k_prep(const float* __restrict__ inp,
                       const float* __restrict__ pat,
                       unsigned* __restrict__ chars32,
                       unsigned* __restrict__ tabs) {
    int bx = blockIdx.x;
    if (bx < B_ * (T_ / 1024)) {
        // ---- r5 k_chars body ----
        int b = bx >> 3;
        int t = ((bx & 7) << 10) + (threadIdx.x << 2);
        const float* base = inp + (size_t)b * C_ * T_ + t;
        float ax = 0.f, ay = 0.f, az = 0.f, aw = 0.f;
        #pragma unroll
        for (int c = 0; c < C_; ++c) {
            float4 v = *(const float4*)(base + (size_t)c * T_);
            float fc = (float)c;
            ax += fc * v.x; ay += fc * v.y; az += fc * v.z; aw += fc * v.w;
        }
        unsigned w = ((unsigned)(ax + 0.5f))
                   | ((unsigned)(ay + 0.5f) << 8)
                   | ((unsigned)(az + 0.5f) << 16)
                   | ((unsigned)(aw + 0.5f) << 24);
        chars32[((size_t)b * T_ + t) >> 2] = w;
    } else {
        // ---- r5 k_disc body (tabs derivation) ----
        for (int i = threadIdx.x; i < P_ * N_; i += 256) {
            int p = i / N_;
            int n = i - p * N_;
            float maxv = -3.402823466e+38f;
            float sum = 0.0f;
            unsigned mask = 0u;
            #pragma unroll
            for (int c = 0; c < C_; ++c) {
                float v = pat[((size_t)c * P_ + p) * N_ + n];
                sum += v;
                if (v > maxv) { maxv = v; mask = (1u << c); }
                else if (v == maxv) { mask |= (1u << c); }
            }
            if (!(sum > 0.0f)) mask = 0u;
            int pc = __popc(mask);
            unsigned req = (unsigned)(__ffs((int)mask) - 1);
            unsigned xs = (pc == 1) ? req * 0x01010101u : 0x7F7F7F7Fu;
            unsigned om = (pc == 0) ? 0u : 0x80808080u;
            tabs[n * 12 + p]     = xs;
            tabs[n * 12 + 6 + p] = om;
        }
    }
}

// ---------------------------------------------------------------------------
// Kernel 2 (verbatim r5, measured 33.2us = write roofline): grid (8,8,32),
// LDS chars staging, byte-SIMD match, 32-n loop, one float4 store/thread/n.
// ---------------------------------------------------------------------------
__global__ void k_final(const unsigned char* __restrict__ chars,
                        const unsigned* __restrict__ tabs,
                        float* __restrict__ out) {
    __shared__ unsigned s32[258];         // 1024 chars + 8 halo bytes
    int tc  = blockIdx.x;                 // 0..7
    int ng  = blockIdx.y;                 // 0..7  (group of 32 n)
    int b   = blockIdx.z;                 // 0..31
    int tid = threadIdx.x;
    int t0  = tc << 10;
    int tb  = t0 + (tid << 2);

    const unsigned* csrc = (const unsigned*)(chars + (size_t)b * T_ + t0);
    s32[tid] = csrc[tid];
    if (tid < 2) {
        unsigned v = 0u;
        int gt = t0 + 1024 + tid * 4;     // byte index into chars[b][*]
        if (gt < T_) v = csrc[256 + tid];
        s32[256 + tid] = v;
    }
    __syncthreads();

    unsigned w0 = s32[tid], w1 = s32[tid + 1], w2 = s32[tid + 2];
    unsigned cw0 = w0;
    unsigned cw1 = __builtin_amdgcn_alignbyte(w1, w0, 1);
    unsigned cw2 = __builtin_amdgcn_alignbyte(w1, w0, 2);
    unsigned cw3 = __builtin_amdgcn_alignbyte(w1, w0, 3);
    unsigned cw4 = w1;
    unsigned cw5 = __builtin_amdgcn_alignbyte(w2, w1, 1);

    int n0 = ng << 5;
    const uint4* tp = (const uint4*)tabs + (size_t)n0 * 3;
    float* obase = out + ((size_t)(b * N_ + n0)) * T_ + tb;
    bool tail = (tc == 7) && (tb + 3 >= TV_);

    #pragma unroll 4
    for (int g = 0; g < 32; ++g) {
        uint4 A  = tp[g * 3 + 0];         // xs0..xs3   (uniform -> s_load)
        uint4 Bv = tp[g * 3 + 1];         // xs4, xs5, om0, om1
        uint4 Cv = tp[g * 3 + 2];         // om2..om5

        unsigned orv;
        orv  = ((cw0 ^ A.x)  + 0x7F7F7F7FU) & Bv.z;
        orv |= ((cw1 ^ A.y)  + 0x7F7F7F7FU) & Bv.w;   // v_and_or_b32
        orv |= ((cw2 ^ A.z)  + 0x7F7F7F7FU) & Cv.x;
        orv |= ((cw3 ^ A.w)  + 0x7F7F7F7FU) & Cv.y;
        orv |= ((cw4 ^ Bv.x) + 0x7F7F7F7FU) & Cv.z;
        orv |= ((cw5 ^ Bv.y) + 0x7F7F7F7FU) & Cv.w;

        float res[4];
        #pragma unroll
        for (int j = 0; j < 4; ++j)
            res[j] = (orv & (0x80u << (8 * j))) ? 0.0f : 1.0f;

        if (tail) {                       // only last chunk's tail lanes
            unsigned act = Bv.z | Bv.w | Cv.x | Cv.y | Cv.z | Cv.w;
            float padf = (act == 0u) ? 1.0f : 0.0f;  // psum==0: pad matches
            #pragma unroll
            for (int j = 0; j < 4; ++j)
                if (tb + j >= TV_) res[j] = padf;
        }

        float4 r; r.x = res[0]; r.y = res[1]; r.z = res[2]; r.w = res[3];
        *(float4*)(obase + (size_t)g * T_) = r;
    }
}

// ---------------------------------------------------------------------------
extern "C" void kernel_launch(void* const* d_in, const int* in_sizes, int n_in,
                              void* d_out, int out_size, void* d_ws, size_t ws_size,
                              hipStream_t stream) {
    const float* input_   = (const float*)d_in[0];   // (B,C,T,1) one-hot fp32
    const float* patterns = (const float*)d_in[1];   // (C,P,1,N) fp32
    float* out = (float*)d_out;                      // (B,N,T,1) fp32

    // ws layout: [0, 12288) tabs (N*12 u32); [16384, 16384+256K) chars u8
    unsigned*      tabs  = (unsigned*)d_ws;
    unsigned char* chars = (unsigned char*)d_ws + 16384;

    hipLaunchKernelGGL(k_prep, dim3(B_ * (T_ / 1024) + 1), dim3(256), 0, stream,
                       input_, patterns, (unsigned*)chars, tabs);
    hipLaunchKernelGGL(k_final, dim3(T_ / 1024, N_ / 32, B_), dim3(256), 0, stream,
                       chars, tabs, out);
}

// Round 13
// 61.573 us; speedup vs baseline: 2.3797x; 2.1541x over previous
//
#include <hip/hip_runtime.h>

// Problem constants (from reference)
#define B_ 32
#define C_ 32
#define T_ 8192
#define N_ 256
#define P_ 6
#define TV_ (T_ - P_ + 1)   // valid conv length = 8187

// ---------------------------------------------------------------------------
// Kernel 1 (verbatim r5): decode one-hot (B,C,T,1) -> chars[B][T] (u8 in u32).
// ---------------------------------------------------------------------------
__global__ void k_chars(const float* __restrict__ inp, unsigned* __restrict__ chars32) {
    int bx = blockIdx.x;                  // [0, B * T/1024)
    int b  = bx >> 3;                     // T/1024 = 8 chunks per batch
    int t  = ((bx & 7) << 10) + (threadIdx.x << 2);
    const float* base = inp + (size_t)b * C_ * T_ + t;
    float ax = 0.f, ay = 0.f, az = 0.f, aw = 0.f;
    #pragma unroll
    for (int c = 0; c < C_; ++c) {
        float4 v = *(const float4*)(base + (size_t)c * T_);
        float fc = (float)c;
        ax += fc * v.x; ay += fc * v.y; az += fc * v.z; aw += fc * v.w;
    }
    unsigned w = ((unsigned)(ax + 0.5f))
               | ((unsigned)(ay + 0.5f) << 8)
               | ((unsigned)(az + 0.5f) << 16)
               | ((unsigned)(aw + 0.5f) << 24);
    chars32[((size_t)b * T_ + t) >> 2] = w;
}

// ---------------------------------------------------------------------------
// Kernel 2: r5 k_final + IN-BLOCK tab derivation (kills the k_disc node).
// Threads 0..191 each derive one (p, n_local) table entry from `pat`
// (32 independent strided loads; pat = 192 KB -> L2-resident), into LDS.
// Single barrier covers chars staging + tab derivation. Match loop is
// verbatim r5, reading tabs from LDS (uniform addr -> broadcast).
// ---------------------------------------------------------------------------
__global__ void k_final(const unsigned char* __restrict__ chars,
                        const float* __restrict__ pat,
                        float* __restrict__ out) {
    __shared__ unsigned s32[258];         // 1024 chars + 8 halo bytes
    __shared__ unsigned s_tabs[32 * 12];  // this block's 32-n tab slice
    int tc  = blockIdx.x;                 // 0..7
    int ng  = blockIdx.y;                 // 0..7  (group of 32 n)
    int b   = blockIdx.z;                 // 0..31
    int tid = threadIdx.x;
    int t0  = tc << 10;
    int tb  = t0 + (tid << 2);
    int n0  = ng << 5;

    // ---- stage chars chunk (verbatim r5) ----
    const unsigned* csrc = (const unsigned*)(chars + (size_t)b * T_ + t0);
    s32[tid] = csrc[tid];
    if (tid < 2) {
        unsigned v = 0u;
        int gt = t0 + 1024 + tid * 4;     // byte index into chars[b][*]
        if (gt < T_) v = csrc[256 + tid];
        s32[256 + tid] = v;
    }

    // ---- derive this block's 32-n x 6-p tab slice (r5 k_disc math) ----
    if (tid < 192) {
        int nl = tid & 31;                // n_local
        int p  = tid >> 5;                // 0..5
        int n  = n0 + nl;
        float maxv = -3.402823466e+38f;
        float sum = 0.0f;
        unsigned mask = 0u;
        #pragma unroll
        for (int c = 0; c < C_; ++c) {
            float v = pat[((size_t)c * P_ + p) * N_ + n];
            sum += v;
            if (v > maxv) { maxv = v; mask = (1u << c); }
            else if (v == maxv) { mask |= (1u << c); }
        }
        if (!(sum > 0.0f)) mask = 0u;
        int pc = __popc(mask);
        unsigned req = (unsigned)(__ffs((int)mask) - 1);
        s_tabs[nl * 12 + p]     = (pc == 1) ? req * 0x01010101u : 0x7F7F7F7Fu;
        s_tabs[nl * 12 + 6 + p] = (pc == 0) ? 0u : 0x80808080u;
    }
    __syncthreads();

    // ---- match loop (verbatim r5), tabs now from LDS ----
    unsigned w0 = s32[tid], w1 = s32[tid + 1], w2 = s32[tid + 2];
    unsigned cw0 = w0;
    unsigned cw1 = __builtin_amdgcn_alignbyte(w1, w0, 1);
    unsigned cw2 = __builtin_amdgcn_alignbyte(w1, w0, 2);
    unsigned cw3 = __builtin_amdgcn_alignbyte(w1, w0, 3);
    unsigned cw4 = w1;
    unsigned cw5 = __builtin_amdgcn_alignbyte(w2, w1, 1);

    const uint4* tp = (const uint4*)s_tabs;
    float* obase = out + ((size_t)(b * N_ + n0)) * T_ + tb;
    bool tail = (tc == 7) && (tb + 3 >= TV_);

    #pragma unroll 4
    for (int g = 0; g < 32; ++g) {
        uint4 A  = tp[g * 3 + 0];         // xs0..xs3  (uniform -> broadcast)
        uint4 Bv = tp[g * 3 + 1];         // xs4, xs5, om0, om1
        uint4 Cv = tp[g * 3 + 2];         // om2..om5

        unsigned orv;
        orv  = ((cw0 ^ A.x)  + 0x7F7F7F7FU) & Bv.z;
        orv |= ((cw1 ^ A.y)  + 0x7F7F7F7FU) & Bv.w;   // v_and_or_b32
        orv |= ((cw2 ^ A.z)  + 0x7F7F7F7FU) & Cv.x;
        orv |= ((cw3 ^ A.w)  + 0x7F7F7F7FU) & Cv.y;
        orv |= ((cw4 ^ Bv.x) + 0x7F7F7F7FU) & Cv.z;
        orv |= ((cw5 ^ Bv.y) + 0x7F7F7F7FU) & Cv.w;

        float res[4];
        #pragma unroll
        for (int j = 0; j < 4; ++j)
            res[j] = (orv & (0x80u << (8 * j))) ? 0.0f : 1.0f;

        if (tail) {                       // only last chunk's tail lanes
            unsigned act = Bv.z | Bv.w | Cv.x | Cv.y | Cv.z | Cv.w;
            float padf = (act == 0u) ? 1.0f : 0.0f;  // psum==0: pad matches
            #pragma unroll
            for (int j = 0; j < 4; ++j)
                if (tb + j >= TV_) res[j] = padf;
        }

        float4 r; r.x = res[0]; r.y = res[1]; r.z = res[2]; r.w = res[3];
        *(float4*)(obase + (size_t)g * T_) = r;
    }
}

// ---------------------------------------------------------------------------
extern "C" void kernel_launch(void* const* d_in, const int* in_sizes, int n_in,
                              void* d_out, int out_size, void* d_ws, size_t ws_size,
                              hipStream_t stream) {
    const float* input_   = (const float*)d_in[0];   // (B,C,T,1) one-hot fp32
    const float* patterns = (const float*)d_in[1];   // (C,P,1,N) fp32
    float* out = (float*)d_out;                      // (B,N,T,1) fp32

    // ws layout: [16384, 16384+256K) chars u8 (tabs no longer materialized)
    unsigned char* chars = (unsigned char*)d_ws + 16384;

    hipLaunchKernelGGL(k_chars, dim3(B_ * (T_ / 1024)), dim3(256), 0, stream,
                       input_, (unsigned*)chars);
    hipLaunchKernelGGL(k_final, dim3(T_ / 1024, N_ / 32, B_), dim3(256), 0, stream,
                       chars, patterns, out);
}